// Round 6
// baseline (232.766 us; speedup 1.0000x reference)
//
#include <hip/hip_runtime.h>
#include <hip/hip_bf16.h>

#define DIMD 1024
#define HIDD 128
#define SEQ  8192
#define BATCH 4
#define KEEP 1024

typedef __attribute__((ext_vector_type(8))) short short8;
typedef __attribute__((ext_vector_type(8))) _Float16 f16x8;
typedef __attribute__((ext_vector_type(4))) float f32x4;
typedef __attribute__((ext_vector_type(4))) unsigned int u32x4;

__device__ __forceinline__ float gelu_exact(float h) {
    return 0.5f * h * (1.0f + erff(h * 0.70710678118654752440f));
}
__device__ __forceinline__ void gload_lds16(const void* g, void* l) {
    __builtin_amdgcn_global_load_lds(
        (const __attribute__((address_space(1))) void*)g,
        (__attribute__((address_space(3))) void*)l, 16, 0, 0);
}

// ---------- Kernel 0: split W1 into 2 f16 limbs (lo pre-scaled by 2^12), -----
// written as pre-swizzled LDS tile images: img[limb][kt][c*128 + 16*(j^(c&7))]
__global__ __launch_bounds__(256)
void w1split_kernel(const float* __restrict__ W1, char* __restrict__ img) {
    const int t = blockIdx.x * 256 + threadIdx.x;   // 16384 = 128c * 8j * 16kt
    const int c = t & 127;
    const int j = (t >> 7) & 7;
    const int kt = t >> 10;
    f16x8 hv, lv;
#pragma unroll
    for (int i = 0; i < 8; ++i) {
        const float f = W1[(kt * 64 + j * 8 + i) * 128 + c];  // W1 is [k][c]
        const _Float16 h = (_Float16)f;
        const _Float16 l = (_Float16)((f - (float)h) * 4096.0f);
        hv[i] = h; lv[i] = l;
    }
    const int off = kt * 16384 + c * 128 + 16 * (j ^ (c & 7));
    *(f16x8*)(img + off) = hv;
    *(f16x8*)(img + 262144 + off) = lv;
}

// ---------- Kernel 1: MFMA scorer, f16 2-limb, software-pipelined ------------
// BM=64, BN=128, BK=64. 4 waves in 2x2. A reg-prefetched (T14), B LDS
// double-buffered with loads spanning raw s_barriers (counted-wait via
// issue order: wait-for-A(t) regs drains older B(t) gloads by vmcnt FIFO).
__global__ __launch_bounds__(256, 2)
void score_mfma(const float* __restrict__ x, const char* __restrict__ w1img,
                const float* __restrict__ b1, const float* __restrict__ W2,
                const float* __restrict__ b2, float* __restrict__ scores) {
    __shared__ __align__(16) char lds[81920];
    char* const Ah  = lds;            // [64 rows][128B] f16 hi, swizzled
    char* const Al  = lds + 8192;     // lo (pre-scaled 2^12)
    char* const Bh0 = lds + 16384;    // B double buffers [128 cols][128B]
    char* const Bl0 = lds + 32768;
    char* const Bh1 = lds + 49152;
    char* const Bl1 = lds + 65536;

    const int tid = threadIdx.x;
    const int lane = tid & 63;
    const int wid = tid >> 6;
    const int wm = wid >> 1;     // row half (32 rows)
    const int wn = wid & 1;      // col half (64 cols)
    const long rowBase = (long)blockIdx.x * 64;

    const int arow = tid >> 2, aq = tid & 3;
    const float* gxBase = x + (rowBase + arow) * DIMD + aq * 16;

    f32x4 acc[2][4], acc2[2][4];
#pragma unroll
    for (int m = 0; m < 2; ++m)
#pragma unroll
        for (int n = 0; n < 4; ++n) {
            acc[m][n] = (f32x4){0.f, 0.f, 0.f, 0.f};
            acc2[m][n] = (f32x4){0.f, 0.f, 0.f, 0.f};
        }

#define STAGE_B(dstH, dstL, tb_) do {                                          \
    const long _tb = (long)(tb_) * 16384;                                      \
    _Pragma("unroll")                                                          \
    for (int i_ = 0; i_ < 4; ++i_) {                                           \
        const int off_ = wid * 4096 + i_ * 1024;                               \
        gload_lds16(w1img + _tb + off_ + lane * 16, (dstH) + off_);            \
        gload_lds16(w1img + 262144 + _tb + off_ + lane * 16, (dstL) + off_);   \
    } } while (0)

#define LOAD_A(kt_) do {                                                       \
    const float* _g = gxBase + (kt_);                                          \
    _Pragma("unroll")                                                          \
    for (int i_ = 0; i_ < 4; ++i_) ra[i_] = *(const f32x4*)(_g + i_ * 4);      \
    } while (0)

#define CONV_WRITE() do {                                                      \
    _Pragma("unroll")                                                          \
    for (int j_ = 0; j_ < 2; ++j_) {                                           \
        f16x8 hv_, lv_;                                                        \
        _Pragma("unroll")                                                      \
        for (int i_ = 0; i_ < 4; ++i_) {                                       \
            const float a0_ = ra[2 * j_][i_], a1_ = ra[2 * j_ + 1][i_];        \
            const _Float16 h0_ = (_Float16)a0_, h1_ = (_Float16)a1_;           \
            hv_[i_] = h0_; hv_[4 + i_] = h1_;                                  \
            lv_[i_] = (_Float16)((a0_ - (float)h0_) * 4096.0f);                \
            lv_[4 + i_] = (_Float16)((a1_ - (float)h1_) * 4096.0f);            \
        }                                                                      \
        const int off_ = arow * 128 + ((aq * 32 + j_ * 16) ^ ((arow & 7) << 4));\
        *(f16x8*)(Ah + off_) = hv_;                                            \
        *(f16x8*)(Al + off_) = lv_;                                            \
    } } while (0)

#define COMPUTE(BhC, BlC) do {                                                 \
    _Pragma("unroll")                                                          \
    for (int ks_ = 0; ks_ < 2; ++ks_) {                                        \
        const int kbase_ = ks_ * 64 + (lane >> 4) * 16;                        \
        f16x8 ahf_[2], alf_[2];                                                \
        _Pragma("unroll")                                                      \
        for (int m_ = 0; m_ < 2; ++m_) {                                       \
            const int r_ = wm * 32 + m_ * 16 + (lane & 15);                    \
            const int off_ = r_ * 128 + (kbase_ ^ ((r_ & 7) << 4));            \
            ahf_[m_] = *(const f16x8*)(Ah + off_);                             \
            alf_[m_] = *(const f16x8*)(Al + off_);                             \
        }                                                                      \
        _Pragma("unroll")                                                      \
        for (int n_ = 0; n_ < 4; ++n_) {                                       \
            const int c_ = wn * 64 + n_ * 16 + (lane & 15);                    \
            const int off_ = c_ * 128 + (kbase_ ^ ((c_ & 7) << 4));            \
            const f16x8 bhf_ = *(const f16x8*)((BhC) + off_);                  \
            const f16x8 blf_ = *(const f16x8*)((BlC) + off_);                  \
            _Pragma("unroll")                                                  \
            for (int m_ = 0; m_ < 2; ++m_) {                                   \
                acc[m_][n_]  = __builtin_amdgcn_mfma_f32_16x16x32_f16(ahf_[m_], bhf_, acc[m_][n_], 0, 0, 0); \
                acc2[m_][n_] = __builtin_amdgcn_mfma_f32_16x16x32_f16(ahf_[m_], blf_, acc2[m_][n_], 0, 0, 0); \
                acc2[m_][n_] = __builtin_amdgcn_mfma_f32_16x16x32_f16(alf_[m_], bhf_, acc2[m_][n_], 0, 0, 0); \
            }                                                                  \
        }                                                                      \
    } } while (0)

#define ITER(t_, BhC, BlC, BhN, BlN) do {                                      \
    STAGE_B(BhN, BlN, ((t_) + 1) & 15);          /* B(t+1) -> other buffer */  \
    CONV_WRITE();                   /* waits ra=A(t); FIFO-drains B(t) too */  \
    LOAD_A((((t_) + 1) & 15) * 64);              /* A(t+1) -> regs        */   \
    asm volatile("s_waitcnt lgkmcnt(0)" ::: "memory");                         \
    __builtin_amdgcn_s_barrier();                                              \
    __builtin_amdgcn_sched_barrier(0);                                         \
    COMPUTE(BhC, BlC);                                                         \
    asm volatile("s_waitcnt lgkmcnt(0)" ::: "memory");                         \
    __builtin_amdgcn_s_barrier();                                              \
    __builtin_amdgcn_sched_barrier(0);                                         \
    } while (0)

    f32x4 ra[4];
    STAGE_B(Bh0, Bl0, 0);        // B(0)
    LOAD_A(0);                   // A(0)

    for (int t2 = 0; t2 < 16; t2 += 2) {
        ITER(t2,     Bh0, Bl0, Bh1, Bl1);
        ITER(t2 + 1, Bh1, Bl1, Bh0, Bl0);
    }
#undef ITER
#undef COMPUTE
#undef CONV_WRITE
#undef LOAD_A
#undef STAGE_B

    // epilogue: h = acc + 2^-12*acc2 + b1[col]; p = gelu(h)*W2[col]; row-sum
    float rsum[2][4];
#pragma unroll
    for (int m = 0; m < 2; ++m)
#pragma unroll
        for (int r = 0; r < 4; ++r) rsum[m][r] = 0.f;
#pragma unroll
    for (int n = 0; n < 4; ++n) {
        const int col = wn * 64 + n * 16 + (lane & 15);
        const float b1c = b1[col], w2c = W2[col];
#pragma unroll
        for (int m = 0; m < 2; ++m)
#pragma unroll
            for (int r = 0; r < 4; ++r) {
                const float h = acc[m][n][r] + 2.44140625e-4f * acc2[m][n][r] + b1c;
                rsum[m][r] += gelu_exact(h) * w2c;
            }
    }
#pragma unroll
    for (int m = 0; m < 2; ++m)
#pragma unroll
        for (int r = 0; r < 4; ++r) {
#pragma unroll
            for (int o = 1; o < 16; o <<= 1)
                rsum[m][r] += __shfl_xor(rsum[m][r], o, 64);
        }
    __syncthreads();                       // done with tiles; reuse LDS
    float* scpad = (float*)lds;            // [2 halves][64 rows]
    if ((lane & 15) == 0) {
#pragma unroll
        for (int m = 0; m < 2; ++m)
#pragma unroll
            for (int r = 0; r < 4; ++r) {
                const int row = wm * 32 + m * 16 + (lane >> 4) * 4 + r;
                scpad[wn * 64 + row] = rsum[m][r];
            }
    }
    __syncthreads();
    if (tid < 64)
        scores[rowBase + tid] = scpad[tid] + scpad[64 + tid] + b2[0];
}

// ---------- Kernel 2: per-batch radix-select top-1024 + stable compact -------
__device__ __forceinline__ unsigned sortable_u32(float f) {
    unsigned u = __float_as_uint(f);
    return (u & 0x80000000u) ? ~u : (u | 0x80000000u);
}

__global__ __launch_bounds__(1024)
void select_kernel(const float* __restrict__ scores, int* __restrict__ idx_out,
                   float* __restrict__ out_tail) {
    const int b = blockIdx.x;
    const int t = threadIdx.x;
    const int wave = t >> 6, lane = t & 63;

    __shared__ unsigned wh[16 * 256];
    __shared__ unsigned wsum[16];
    __shared__ unsigned sbc_bin, sbc_sub;

    unsigned key[8];
    {
        const float* sc = scores + b * SEQ + t * 8;
        f32x4 v0 = *(const f32x4*)(sc);
        f32x4 v1 = *(const f32x4*)(sc + 4);
#pragma unroll
        for (int i = 0; i < 4; ++i) {
            key[i] = sortable_u32(v0[i]);
            key[4 + i] = sortable_u32(v1[i]);
        }
    }

    unsigned prefix = 0, need = KEEP;
    for (int r = 0; r < 4; ++r) {
        const int shift = 24 - 8 * r;
        const unsigned mask_hi = (r == 0) ? 0u : (0xFFFFFFFFu << (shift + 8));
#pragma unroll
        for (int i = 0; i < 4; ++i) wh[t + i * 1024] = 0;
        __syncthreads();
#pragma unroll
        for (int j = 0; j < 8; ++j)
            if ((key[j] & mask_hi) == prefix)
                atomicAdd(&wh[wave * 256 + ((key[j] >> shift) & 255u)], 1u);
        __syncthreads();
        if (t < 256) {
            unsigned s = 0;
#pragma unroll
            for (int w = 0; w < 16; ++w) s += wh[w * 256 + t];
            wh[t] = s;
        }
        __syncthreads();
        if (wave == 0) {
            const unsigned h0 = wh[lane * 4 + 0], h1 = wh[lane * 4 + 1];
            const unsigned h2 = wh[lane * 4 + 2], h3 = wh[lane * 4 + 3];
            const unsigned s3 = h3, s2 = h2 + s3, s1 = h1 + s2, s0 = h0 + s1;
            unsigned run = s0;
#pragma unroll
            for (int d = 1; d < 64; d <<= 1) {
                const unsigned v = __shfl_down(run, d, 64);
                if (lane + d < 64) run += v;
            }
            const unsigned above = run - s0;            // suffix of bin 4(lane+1)
            const unsigned suf0 = above + s0, suf1 = above + s1;
            const unsigned suf2 = above + s2, suf3 = above + s3;
            if (suf1 < need && need <= suf0) { sbc_bin = lane * 4 + 0; sbc_sub = suf1; }
            if (suf2 < need && need <= suf1) { sbc_bin = lane * 4 + 1; sbc_sub = suf2; }
            if (suf3 < need && need <= suf2) { sbc_bin = lane * 4 + 2; sbc_sub = suf3; }
            if (above < need && need <= suf3) { sbc_bin = lane * 4 + 3; sbc_sub = above; }
        }
        __syncthreads();
        prefix |= sbc_bin << shift;
        need -= sbc_sub;
        __syncthreads();
    }
    const unsigned tau = prefix;   // key value of the 1024th-largest
    const unsigned m = need;       // #ties (==tau) to keep, lowest-index first

    // packed (gt<<16 | eq) stable scan in index order (verified rounds 1/4/5)
    unsigned pk[8], tsum = 0;
#pragma unroll
    for (int j = 0; j < 8; ++j) {
        const unsigned gt = (key[j] > tau) ? 1u : 0u;
        const unsigned eq = (key[j] == tau) ? 1u : 0u;
        pk[j] = tsum;
        tsum += (gt << 16) | eq;
    }
    unsigned incl = tsum;
#pragma unroll
    for (int d = 1; d < 64; d <<= 1) {
        const unsigned v = __shfl_up(incl, d, 64);
        if (lane >= d) incl += v;
    }
    if (lane == 63) wsum[wave] = incl;
    __syncthreads();
    if (t == 0) {
        unsigned run = 0;
        for (int w = 0; w < 16; ++w) { const unsigned tmp = wsum[w]; wsum[w] = run; run += tmp; }
    }
    __syncthreads();
    const unsigned base = wsum[wave] + (incl - tsum);

#pragma unroll
    for (int j = 0; j < 8; ++j) {
        const unsigned before = base + pk[j];
        const unsigned gt_before = before >> 16;
        const unsigned eq_before = before & 0xFFFFu;
        const bool keep = (key[j] > tau) || (key[j] == tau && eq_before < m);
        if (keep) {
            const unsigned pos = gt_before + (eq_before < m ? eq_before : m);
            const int idx = t * 8 + j;
            idx_out[b * KEEP + pos] = idx;
            out_tail[b * KEEP + pos] = (float)idx;
        }
    }
}

// ---------- Kernel 3: gather kept tokens -------------------------------------
__global__ __launch_bounds__(256)
void gather_kernel(const float* __restrict__ x, const int* __restrict__ idx,
                   float* __restrict__ out) {
    const int j = blockIdx.x;          // 0..4095 = b*1024 + pos
    const int b = j >> 10;
    const int id = idx[j];
    const f32x4* src = (const f32x4*)(x + ((long)b * SEQ + id) * DIMD);
    f32x4* dst = (f32x4*)(out + (long)j * DIMD);
    dst[threadIdx.x] = src[threadIdx.x];
}

extern "C" void kernel_launch(void* const* d_in, const int* in_sizes, int n_in,
                              void* d_out, int out_size, void* d_ws, size_t ws_size,
                              hipStream_t stream) {
    const float* x  = (const float*)d_in[0];
    const float* W1 = (const float*)d_in[1];
    const float* b1 = (const float*)d_in[2];
    const float* W2 = (const float*)d_in[3];
    const float* b2 = (const float*)d_in[4];
    float* out = (float*)d_out;

    char* ws = (char*)d_ws;
    char*  w1img  = ws;                               // 2 x 256KB limb images
    float* scores = (float*)(ws + 524288);            // 128KB
    int*   idxbuf = (int*)(ws + 524288 + 131072);     // 16KB

    w1split_kernel<<<64, 256, 0, stream>>>(W1, w1img);
    score_mfma<<<(BATCH * SEQ) / 64, 256, 0, stream>>>(x, w1img, b1, W2, b2, scores);
    select_kernel<<<BATCH, 1024, 0, stream>>>(scores, idxbuf,
                                              out + (long)BATCH * KEEP * DIMD);
    gather_kernel<<<BATCH * KEEP, 256, 0, stream>>>(x, idxbuf, out);
}